// Round 12
// baseline (686.912 us; speedup 1.0000x reference)
//
#include <hip/hip_runtime.h>
#include <hip/hip_bf16.h>
#include <math.h>

// EnhancedTransformerBlock on MI355X — Round 12:
//  * gemm_hi_k at 5 blocks/CU (LDS 5x32KB = 160KB exactly), lda param.
//  * FFN1+gate1 fused into one N=4608 GEMM (per-column GELU/ReLU split),
//    output hgb[8192][4608]; FFN2/gate2 read strided slices of it.
//  * FFN2/gate2 outputs bf16; adaLN2 reads bf16 ffn/g (-48MB traffic).
//  * attn v3 / adaLN structure unchanged from round 8.

#define HDIM 1024
#define NHEAD 16
#define DHEAD 64
#define NBATCH 8
#define NSEQ 1024
#define NTOK (NBATCH * NSEQ)   // 8192
#define QKVSTR 3072
#define LNEPS 1e-5f
#define LOG2E_8 0.180336880f   // log2(e)/8

using f32x4 = __attribute__((ext_vector_type(4))) float;
using s16x8 = __attribute__((ext_vector_type(8))) short;
using u16x8 = __attribute__((ext_vector_type(8))) unsigned short;

enum { ACT_NONE = 0, ACT_GELU = 1, ACT_RELU = 2, ACT_SIG = 3, ACT_GR = 4 };

__device__ inline float bf2f(unsigned short u) {
    union { unsigned u; float f; } t; t.u = ((unsigned)u) << 16; return t.f;
}
__device__ inline unsigned short f2bf(float f) {
    __hip_bfloat16 h = __float2bfloat16(f);
    return *reinterpret_cast<unsigned short*>(&h);
}
__device__ inline float gelu_f(float t) {
    const float u = t * (0.7978845608f + 0.0356774081f * t * t);
    const float e = __expf(2.f * u);
    const float th = 1.f - 2.f / (e + 1.f);
    return 0.5f * t * (1.f + th);
}

#define GLDS16(g, l) __builtin_amdgcn_global_load_lds( \
    (__attribute__((address_space(1))) void*)(g),      \
    (__attribute__((address_space(3))) void*)(l), 16, 0, 0)
#define MFMA16(a, b, c) __builtin_amdgcn_mfma_f32_16x16x32_bf16(a, b, c, 0, 0, 0)
#define BAR() __builtin_amdgcn_s_barrier()
#define LGKM0() do { asm volatile("s_waitcnt lgkmcnt(0)" ::: "memory"); \
                     __builtin_amdgcn_sched_barrier(0); } while (0)

template<int N> __device__ __forceinline__ void vmwait() {
    asm volatile("s_waitcnt vmcnt(%0)" :: "i"(N) : "memory");
}

// ---------------------------------------------------------------------------
__global__ __launch_bounds__(256)
void cast_bf16_k(const float* __restrict__ in, unsigned short* __restrict__ out, int n4)
{
    for (int i = blockIdx.x * 256 + threadIdx.x; i < n4; i += gridDim.x * 256) {
        float4 v = ((const float4*)in)[i];
        ushort4 o;
        o.x = f2bf(v.x); o.y = f2bf(v.y); o.z = f2bf(v.z); o.w = f2bf(v.w);
        ((ushort4*)out)[i] = o;
    }
}

// ---------------------------------------------------------------------------
__global__ __launch_bounds__(256)
void concat3_k(const float* __restrict__ a, const float* __restrict__ b,
               const float* __restrict__ c, float* __restrict__ o)
{
    int i = blockIdx.x * 256 + threadIdx.x;   // grid 12 -> 3072
    o[i] = i < 1024 ? a[i] : (i < 2048 ? b[i - 1024] : c[i - 2048]);
}

__global__ __launch_bounds__(256)
void concat2_k(const float* __restrict__ a, const float* __restrict__ b,
               float* __restrict__ o)
{
    int i = blockIdx.x * 256 + threadIdx.x;   // grid 18 -> 4608
    o[i] = i < 4096 ? a[i] : b[i - 4096];
}

// ---------------------------------------------------------------------------
__global__ __launch_bounds__(256)
void transpose_cast_k(const float* __restrict__ W, unsigned short* __restrict__ Wt,
                      int K, int N)
{
    __shared__ float tile[32][33];
    const int tx = threadIdx.x, ty = threadIdx.y;
    const int k0 = blockIdx.y * 32, n0 = blockIdx.x * 32;
#pragma unroll
    for (int r = 0; r < 32; r += 8)
        tile[ty + r][tx] = W[(size_t)(k0 + ty + r) * N + n0 + tx];
    __syncthreads();
#pragma unroll
    for (int r = 0; r < 32; r += 8)
        Wt[(size_t)(n0 + ty + r) * K + k0 + tx] = f2bf(tile[tx][ty + r]);
}

__global__ __launch_bounds__(256)
void transpose_cast4_k(const float* __restrict__ W0, const float* __restrict__ W1,
                       const float* __restrict__ W2, const float* __restrict__ W3,
                       unsigned short* __restrict__ Wt)
{
    __shared__ float tile[32][33];
    const int z = blockIdx.z;
    const float* W = z == 0 ? W0 : z == 1 ? W1 : z == 2 ? W2 : W3;
    unsigned short* dst = Wt + (size_t)z * HDIM * HDIM;
    const int tx = threadIdx.x, ty = threadIdx.y;
    const int k0 = blockIdx.y * 32, n0 = blockIdx.x * 32;
#pragma unroll
    for (int r = 0; r < 32; r += 8)
        tile[ty + r][tx] = W[(size_t)(k0 + ty + r) * HDIM + n0 + tx];
    __syncthreads();
#pragma unroll
    for (int r = 0; r < 32; r += 8)
        dst[(size_t)(n0 + ty + r) * HDIM + k0 + tx] = f2bf(tile[tx][ty + r]);
}

// ---------------------------------------------------------------------------
__global__ __launch_bounds__(256)
void transpose_v_k(const unsigned short* __restrict__ vb, unsigned short* __restrict__ vtb)
{
    __shared__ unsigned short t[64][72];
    const int tid = threadIdx.x;
    const int b = blockIdx.z, h = blockIdx.y;
    const int s0 = blockIdx.x * 64;
    {
        const int r = tid >> 3, c = (tid & 7) * 8;
        *(u16x8*)&t[r][c] =
            *(const u16x8*)&vb[((size_t)(b * NSEQ + s0 + r)) * QKVSTR + h * DHEAD + c];
        *(u16x8*)&t[r + 32][c] =
            *(const u16x8*)&vb[((size_t)(b * NSEQ + s0 + r + 32)) * QKVSTR + h * DHEAD + c];
    }
    __syncthreads();
    {
        const int d = tid & 63, sc = (tid >> 6) * 16;
        u16x8 o0, o1;
#pragma unroll
        for (int i = 0; i < 8; ++i) o0[i] = t[sc + i][d];
#pragma unroll
        for (int i = 0; i < 8; ++i) o1[i] = t[sc + 8 + i][d];
        unsigned short* dst = &vtb[((size_t)((b * NHEAD + h) * DHEAD + d)) * NSEQ + s0 + sc];
        *(u16x8*)dst = o0;
        *(u16x8*)(dst + 8) = o1;
    }
}

// ---------------------------------------------------------------------------
// High-occupancy GEMM: C[M,N] = act(A[M,K](lda) @ Bt[N,K]^T + bias (+add)).
// 128x128 tile, BK=32, 256 threads (4 waves 2x2), static 32 KiB LDS dbuf,
// granule-XOR swizzle (0 conflicts), counted vmcnt(4). 5 blocks/CU.
// ---------------------------------------------------------------------------
template<int ACT, bool HAS_ADD, bool OUT_BF>
__global__ __launch_bounds__(256, 5)
void gemm_hi_k(const unsigned short* __restrict__ A, const unsigned short* __restrict__ Bt,
               const float* __restrict__ bias, const float* __restrict__ add,
               void* __restrict__ Cv, int M, int N, int K, int lda, int nbx)
{
    __shared__ alignas(16) unsigned short As[2][128 * 32];
    __shared__ alignas(16) unsigned short Bs[2][128 * 32];

    const int tid = threadIdx.x;
    const int lane = tid & 63;
    const int w = tid >> 6;
    const int wr = w >> 1, wc = w & 1;
    const int chunk = gridDim.x >> 3;
    const int wg = (blockIdx.x & 7) * chunk + (blockIdx.x >> 3);
    const int m0 = (wg / nbx) * 128;
    const int n0 = (wg % nbx) * 128;

    const int fr = lane & 15;
    const int fo = lane >> 4;
    const int fo_swz8 = (fo ^ ((fr >> 1) & 3)) * 8;

    const int srow = tid >> 2;
    const int sg8 = ((tid & 3) ^ ((tid >> 3) & 3)) * 8;

    f32x4 acc[4][4] = {};

    auto stage = [&](int t) {
        const int buf = t & 1;
        const unsigned short* as_ = A + (size_t)(m0 + srow) * lda + t * 32 + sg8;
        const unsigned short* bs_ = Bt + (size_t)(n0 + srow) * K + t * 32 + sg8;
        GLDS16(as_, &As[buf][(w * 16) * 32]);
        GLDS16(as_ + (size_t)64 * lda, &As[buf][(64 + w * 16) * 32]);
        GLDS16(bs_, &Bs[buf][(w * 16) * 32]);
        GLDS16(bs_ + (size_t)64 * K, &Bs[buf][(64 + w * 16) * 32]);
    };

    const int NT = K / 32;
    stage(0);

    for (int t = 0; t < NT; ++t) {
        if (t + 1 < NT) { stage(t + 1); vmwait<4>(); }
        else            { vmwait<0>(); }
        BAR();

        const int buf = t & 1;
        s16x8 af[4], bf[4];
#pragma unroll
        for (int i = 0; i < 4; ++i)
            af[i] = *(const s16x8*)(&As[buf][(wr * 64 + i * 16 + fr) * 32 + fo_swz8]);
#pragma unroll
        for (int j = 0; j < 4; ++j)
            bf[j] = *(const s16x8*)(&Bs[buf][(wc * 64 + j * 16 + fr) * 32 + fo_swz8]);

        __builtin_amdgcn_s_setprio(1);
#pragma unroll
        for (int i = 0; i < 4; ++i)
#pragma unroll
            for (int j = 0; j < 4; ++j)
                acc[i][j] = MFMA16(af[i], bf[j], acc[i][j]);
        __builtin_amdgcn_s_setprio(0);

        LGKM0();
        BAR();
    }

    float bv[4];
#pragma unroll
    for (int j = 0; j < 4; ++j)
        bv[j] = bias[n0 + wc * 64 + j * 16 + fr];
#pragma unroll
    for (int i = 0; i < 4; ++i) {
#pragma unroll
        for (int j = 0; j < 4; ++j) {
            const int gn = n0 + wc * 64 + j * 16 + fr;
#pragma unroll
            for (int r = 0; r < 4; ++r) {
                const int gm = m0 + wr * 64 + i * 16 + fo * 4 + r;
                float t = acc[i][j][r] + bv[j];
                if (HAS_ADD) t += add[(size_t)gm * N + gn];
                if (ACT == ACT_GELU)      t = gelu_f(t);
                else if (ACT == ACT_RELU) t = fmaxf(t, 0.f);
                else if (ACT == ACT_SIG)  t = 1.f / (1.f + __expf(-t));
                else if (ACT == ACT_GR)   t = (gn < 4096) ? gelu_f(t) : fmaxf(t, 0.f);
                if (OUT_BF) ((unsigned short*)Cv)[(size_t)gm * N + gn] = f2bf(t);
                else        ((float*)Cv)[(size_t)gm * N + gn] = t;
            }
        }
    }
}

// ---------------------------------------------------------------------------
// MFMA flash attention v3 (round-8, unchanged).
// ---------------------------------------------------------------------------
__global__ __launch_bounds__(512, 6)
void attn_k(const unsigned short* __restrict__ QKVb, const unsigned short* __restrict__ Vtb,
            unsigned short* __restrict__ Cb)
{
    __shared__ alignas(16) unsigned short Ks[2][64 * 64];
    __shared__ alignas(16) unsigned short Vs[2][64 * 64];
    __shared__ alignas(16) unsigned short Ps[8][16 * 72];

    const int tid = threadIdx.x;
    const int lane = tid & 63;
    const int wid = tid >> 6;
    const int L = blockIdx.x;
    const int xcd = L & 7, s = L >> 3;
    const int bh = xcd + ((s >> 3) << 3);
    const int qt = s & 7;
    const int b = bh >> 4, h = bh & 15;
    const int q0 = qt * 128 + wid * 16;

    const int kcol = lane & 15;
    const int kofs = (lane >> 4) * 8;
    const size_t qoff = ((size_t)(b * NSEQ + q0 + kcol)) * QKVSTR + h * DHEAD + kofs;
    const s16x8 qf0 = *(const s16x8*)(QKVb + qoff);
    const s16x8 qf1 = *(const s16x8*)(QKVb + qoff + 32);

    f32x4 accO[4] = {};
    float mrow[4] = {-1e30f, -1e30f, -1e30f, -1e30f};
    float lsum[4] = {0.f, 0.f, 0.f, 0.f};

    const int lr = lane >> 3;
    const int swz8 = (((lane & 7) ^ lr)) * 8;
    const size_t kbase  = ((size_t)(b * NSEQ)) * QKVSTR + HDIM + h * DHEAD;
    const size_t vtbase = ((size_t)(bh * DHEAD)) * NSEQ;

    unsigned short* const pw = &Ps[wid][0];
    const int prow = (lane >> 4) * 4;

    auto stage = [&](int kt, int buf) {
        const int rowb = wid * 8;
        GLDS16(QKVb + kbase + (size_t)(kt * 64 + rowb + lr) * QKVSTR + swz8,
               Ks[buf] + rowb * 64);
        GLDS16(Vtb + vtbase + (size_t)(rowb + lr) * NSEQ + kt * 64 + swz8,
               Vs[buf] + rowb * 64);
    };

    stage(0, 0);
    asm volatile("s_waitcnt vmcnt(0)" ::: "memory");
    __syncthreads();

    for (int kt = 0; kt < NSEQ / 64; ++kt) {
        const int cur = kt & 1;
        if (kt + 1 < NSEQ / 64) stage(kt + 1, cur ^ 1);

        f32x4 sa[4];
#pragma unroll
        for (int jt = 0; jt < 4; ++jt) {
            const int kr = jt * 16 + kcol;
            const unsigned swz = ((unsigned)(kr & 7)) << 4;
            const s16x8 kf0 = *(const s16x8*)((const char*)Ks[cur] + kr * 128 + ((kofs * 2) ^ swz));
            const s16x8 kf1 = *(const s16x8*)((const char*)Ks[cur] + kr * 128 + ((64 + kofs * 2) ^ swz));
            f32x4 t = {};
            t = MFMA16(qf0, kf0, t);
            t = MFMA16(qf1, kf1, t);
            sa[jt] = t * LOG2E_8;
        }

        float lmax[4];
#pragma unroll
        for (int r = 0; r < 4; ++r)
            lmax[r] = fmaxf(fmaxf(sa[0][r], sa[1][r]), fmaxf(sa[2][r], sa[3][r]));
        const float guard = fmaxf(fmaxf(lmax[0] - mrow[0], lmax[1] - mrow[1]),
                                  fmaxf(lmax[2] - mrow[2], lmax[3] - mrow[3]));
        if (!__all(guard <= 8.f)) {
#pragma unroll
            for (int r = 0; r < 4; ++r) {
                float m = lmax[r];
                m = fmaxf(m, __shfl_xor(m, 1));
                m = fmaxf(m, __shfl_xor(m, 2));
                m = fmaxf(m, __shfl_xor(m, 4));
                m = fmaxf(m, __shfl_xor(m, 8));
                const float mn = fmaxf(mrow[r], m);
                const float corr = exp2f(mrow[r] - mn);
                mrow[r] = mn;
                lsum[r] *= corr;
#pragma unroll
                for (int dt = 0; dt < 4; ++dt) accO[dt][r] *= corr;
            }
        }
#pragma unroll
        for (int r = 0; r < 4; ++r) {
#pragma unroll
            for (int jt = 0; jt < 4; ++jt) {
                const float p = exp2f(sa[jt][r] - mrow[r]);
                pw[(prow + r) * 72 + jt * 16 + kcol] = f2bf(p);
                lsum[r] += p;
            }
        }

#pragma unroll
        for (int kc = 0; kc < 2; ++kc) {
            const s16x8 pa = *(const s16x8*)(pw + kcol * 72 + kc * 32 + kofs);
#pragma unroll
            for (int dt = 0; dt < 4; ++dt) {
                const int dr = dt * 16 + kcol;
                const unsigned swz = ((unsigned)(dr & 7)) << 4;
                const s16x8 vf = *(const s16x8*)((const char*)Vs[cur] + dr * 128 +
                                                 ((kc * 64 + kofs * 2) ^ swz));
                accO[dt] = MFMA16(pa, vf, accO[dt]);
            }
        }

        if (kt + 1 < NSEQ / 64) asm volatile("s_waitcnt vmcnt(0)" ::: "memory");
        __builtin_amdgcn_s_barrier();
    }

#pragma unroll
    for (int r = 0; r < 4; ++r) {
        lsum[r] += __shfl_xor(lsum[r], 1);
        lsum[r] += __shfl_xor(lsum[r], 2);
        lsum[r] += __shfl_xor(lsum[r], 4);
        lsum[r] += __shfl_xor(lsum[r], 8);
    }

    const size_t obase = ((size_t)(b * NSEQ + q0 + prow)) * HDIM + h * DHEAD;
#pragma unroll
    for (int r = 0; r < 4; ++r) {
        const float rl = 1.f / lsum[r];
#pragma unroll
        for (int dt = 0; dt < 4; ++dt)
            Cb[obase + (size_t)r * HDIM + dt * 16 + kcol] = f2bf(accO[dt][r] * rl);
    }
}

// ---------------------------------------------------------------------------
// ada-LayerNorm. MODE 0: y = a (fp32), also writes bf16 copy.
// MODE 1: y = a*(2-g) + fo*g with fo,g read as bf16.
// ---------------------------------------------------------------------------
template<int MODE, bool WRITE_BF>
__global__ __launch_bounds__(256)
void adaln_k(const float* __restrict__ a,
             const unsigned short* __restrict__ fo_bf,
             const unsigned short* __restrict__ g_bf,
             const float* __restrict__ vol,
             const float* __restrict__ lw, const float* __restrict__ lb,
             const float* __restrict__ gm, const float* __restrict__ bt,
             const float* __restrict__ vsw, const float* __restrict__ vsb,
             float* __restrict__ out, unsigned short* __restrict__ out_bf)
{
    const int tok = blockIdx.x;
    const int tid = threadIdx.x;
    const size_t base = (size_t)tok * HDIM + tid * 4;
    float v[4];
    {
        float4 va = *(const float4*)&a[base];
        if (MODE == 1) {
            ushort4 uf = *(const ushort4*)&fo_bf[base];
            ushort4 ug = *(const ushort4*)&g_bf[base];
            float f0 = bf2f(uf.x), f1 = bf2f(uf.y), f2 = bf2f(uf.z), f3 = bf2f(uf.w);
            float g0 = bf2f(ug.x), g1 = bf2f(ug.y), g2 = bf2f(ug.z), g3 = bf2f(ug.w);
            v[0] = va.x * (2.f - g0) + f0 * g0;
            v[1] = va.y * (2.f - g1) + f1 * g1;
            v[2] = va.z * (2.f - g2) + f2 * g2;
            v[3] = va.w * (2.f - g3) + f3 * g3;
        } else {
            v[0] = va.x; v[1] = va.y; v[2] = va.z; v[3] = va.w;
        }
    }
    float sum = v[0] + v[1] + v[2] + v[3];
    float sq  = v[0]*v[0] + v[1]*v[1] + v[2]*v[2] + v[3]*v[3];
#pragma unroll
    for (int off = 32; off > 0; off >>= 1) {
        sum += __shfl_down(sum, off);
        sq  += __shfl_down(sq, off);
    }
    __shared__ float ssum[4], ssq[4];
    const int wid = tid >> 6, lane = tid & 63;
    if (lane == 0) { ssum[wid] = sum; ssq[wid] = sq; }
    __syncthreads();
    const float tsum = ssum[0] + ssum[1] + ssum[2] + ssum[3];
    const float tsq  = ssq[0]  + ssq[1]  + ssq[2]  + ssq[3];
    const float mu   = tsum * (1.f / 1024.f);
    const float var  = tsq * (1.f / 1024.f) - mu * mu;
    const float rstd = rsqrtf(var + LNEPS);
    const float vsv  = 1.f / (1.f + __expf(-(vol[tok] * vsw[0] + vsb[0])));
    const float sca  = (1.f + vsv) * gm[0];
    const float off2 = bt[0];
    const float4 lwv = *(const float4*)&lw[tid * 4];
    const float4 lbv = *(const float4*)&lb[tid * 4];
    float r0 = ((v[0] - mu) * rstd * lwv.x + lbv.x) * sca + off2;
    float r1 = ((v[1] - mu) * rstd * lwv.y + lbv.y) * sca + off2;
    float r2 = ((v[2] - mu) * rstd * lwv.z + lbv.z) * sca + off2;
    float r3 = ((v[3] - mu) * rstd * lwv.w + lbv.w) * sca + off2;
    *(float4*)&out[base] = make_float4(r0, r1, r2, r3);
    if (WRITE_BF) {
        ushort4 ob;
        ob.x = f2bf(r0); ob.y = f2bf(r1); ob.z = f2bf(r2); ob.w = f2bf(r3);
        *(ushort4*)&out_bf[base] = ob;
    }
}

// ---------------------------------------------------------------------------
extern "C" void kernel_launch(void* const* d_in, const int* in_sizes, int n_in,
                              void* d_out, int out_size, void* d_ws, size_t ws_size,
                              hipStream_t stream)
{
    (void)in_sizes; (void)n_in; (void)out_size; (void)ws_size;
    const float* x    = (const float*)d_in[0];
    const float* vol  = (const float*)d_in[1];
    const float* Wq   = (const float*)d_in[2];  const float* bq  = (const float*)d_in[3];
    const float* Wk   = (const float*)d_in[4];  const float* bk  = (const float*)d_in[5];
    const float* Wv   = (const float*)d_in[6];  const float* bv  = (const float*)d_in[7];
    const float* Wo   = (const float*)d_in[8];  const float* bo  = (const float*)d_in[9];
    const float* ln1w = (const float*)d_in[10]; const float* ln1b = (const float*)d_in[11];
    const float* gm1  = (const float*)d_in[12]; const float* be1 = (const float*)d_in[13];
    const float* vs1w = (const float*)d_in[14]; const float* vs1b = (const float*)d_in[15];
    const float* fw1  = (const float*)d_in[16]; const float* fb1 = (const float*)d_in[17];
    const float* fw2  = (const float*)d_in[18]; const float* fb2 = (const float*)d_in[19];
    const float* gw1  = (const float*)d_in[20]; const float* gb1 = (const float*)d_in[21];
    const float* gw2  = (const float*)d_in[22]; const float* gb2 = (const float*)d_in[23];
    const float* ln2w = (const float*)d_in[24]; const float* ln2b = (const float*)d_in[25];
    const float* gm2  = (const float*)d_in[26]; const float* be2 = (const float*)d_in[27];
    const float* vs2w = (const float*)d_in[28]; const float* vs2b = (const float*)d_in[29];

    char* w = (char*)d_ws;
    auto MB = [](size_t v) { return v << 20; };
    // weights: 0-6 wtqkv | 6-8 wto | 8-16 wtf1 | 16-17 wtg1 (contiguous with
    // wtf1 -> fused [4608][1024]) | 17-25 wtf2 | 25-26 wtg2
    unsigned short* wtqkv = (unsigned short*)(w + MB(0));
    unsigned short* wto   = (unsigned short*)(w + MB(6));
    unsigned short* wtfg  = (unsigned short*)(w + MB(8));   // [4608][1024]
    unsigned short* wtg1  = (unsigned short*)(w + MB(16));
    unsigned short* wtf2  = (unsigned short*)(w + MB(17));
    unsigned short* wtg2  = (unsigned short*)(w + MB(25));
    // activations:
    unsigned short* xb   = (unsigned short*)(w + MB(26));   // 26-42
    unsigned short* qkvb = (unsigned short*)(w + MB(42));   // 42-90
    unsigned short* vtb  = (unsigned short*)(w + MB(90));   // 90-106
    unsigned short* cxb  = (unsigned short*)(w + MB(106));  // 106-122
    float*          ao   = (float*)(w + MB(122));           // 122-154
    float*          x1   = (float*)(w + MB(42));            // 42-74 (qkvb dead)
    unsigned short* x1b  = (unsigned short*)(w + MB(74));   // 74-90
    unsigned short* hgb  = (unsigned short*)(w + MB(90));   // 90-162 [8192][4608]
    unsigned short* ffnb = (unsigned short*)(w + MB(162));  // 162-178
    unsigned short* ggb  = (unsigned short*)(w + MB(26));   // 26-42 (xb dead)
    float*          bqkv = (float*)(w + MB(184));
    float*          bfg  = (float*)(w + MB(185));

    dim3 blk(256);
    dim3 tb(32, 8);
    transpose_cast4_k<<<dim3(32, 32, 4), tb, 0, stream>>>(Wq, Wk, Wv, Wo, wtqkv);
    transpose_cast_k<<<dim3(4096/32, 1024/32), tb, 0, stream>>>(fw1, wtfg, 1024, 4096);
    transpose_cast_k<<<dim3(512/32, 1024/32),  tb, 0, stream>>>(gw1, wtg1, 1024, 512);
    transpose_cast_k<<<dim3(1024/32, 4096/32), tb, 0, stream>>>(fw2, wtf2, 4096, 1024);
    transpose_cast_k<<<dim3(1024/32, 512/32),  tb, 0, stream>>>(gw2, wtg2, 512, 1024);
    cast_bf16_k<<<2048, blk, 0, stream>>>(x, xb, NTOK * HDIM / 4);
    concat3_k<<<12, blk, 0, stream>>>(bq, bk, bv, bqkv);
    concat2_k<<<18, blk, 0, stream>>>(fb1, gb1, bfg);

    // QKV: [8192][1024] @ [3072][1024]^T
    gemm_hi_k<ACT_NONE, false, true><<<dim3(24 * 64), blk, 0, stream>>>(
        xb, wtqkv, bqkv, nullptr, qkvb, NTOK, QKVSTR, HDIM, HDIM, 24);
    transpose_v_k<<<dim3(NSEQ / 64, NHEAD, NBATCH), blk, 0, stream>>>(qkvb + 2048, vtb);
    attn_k<<<dim3(1024), 512, 0, stream>>>(qkvb, vtb, cxb);
    gemm_hi_k<ACT_NONE, true, false><<<dim3(8 * 64), blk, 0, stream>>>(
        cxb, wto, bo, x, ao, NTOK, HDIM, HDIM, HDIM, 8);
    adaln_k<0, true><<<dim3(NTOK), blk, 0, stream>>>(
        ao, nullptr, nullptr, vol, ln1w, ln1b, gm1, be1, vs1w, vs1b, x1, x1b);
    // fused FFN1 + gate1: N = 4608 (GELU cols < 4096, ReLU cols >= 4096)
    gemm_hi_k<ACT_GR, false, true><<<dim3(36 * 64), blk, 0, stream>>>(
        x1b, wtfg, bfg, nullptr, hgb, NTOK, 4608, HDIM, HDIM, 36);
    // FFN2: reads hgb[:, :4096] (lda = 4608)
    gemm_hi_k<ACT_NONE, false, true><<<dim3(8 * 64), blk, 0, stream>>>(
        hgb, wtf2, fb2, nullptr, ffnb, NTOK, HDIM, 4096, 4608, 8);
    // gate2: reads hgb[:, 4096:] (lda = 4608, K = 512)
    gemm_hi_k<ACT_SIG, false, true><<<dim3(8 * 64), blk, 0, stream>>>(
        hgb + 4096, wtg2, gb2, nullptr, ggb, NTOK, HDIM, 512, 4608, 8);
    adaln_k<1, false><<<dim3(NTOK), blk, 0, stream>>>(
        x1, ffnb, ggb, vol, ln2w, ln2b, gm2, be2, vs2w, vs2b, (float*)d_out, nullptr);
}

// Round 13
// 463.932 us; speedup vs baseline: 1.4806x; 1.4806x over previous
//
#include <hip/hip_runtime.h>
#include <hip/hip_bf16.h>
#include <math.h>

// EnhancedTransformerBlock on MI355X — Round 13: revert R12's regressions,
// keep safe wins, fix grid fill.
//  * gemm_hi_k back to 4 blocks/CU (R12 lesson: 5/CU -> per-XCD L2 write-set
//    overflow -> 3.3x write amplification). FFN1/gate1 un-fused.
//  * new BM=64 variant (64x128 tile, 24KB LDS) for N<=1024 shapes:
//    Wo/FFN2/gate2 grids 512 -> 1024 (full machine fill), gate1 256 -> 512.
//  * FFN2/gate2 outputs bf16 + bf16-reading adaLN2 (R12-validated numerics).
//  * attn v3 / adaLN structure unchanged from round 8.

#define HDIM 1024
#define NHEAD 16
#define DHEAD 64
#define NBATCH 8
#define NSEQ 1024
#define NTOK (NBATCH * NSEQ)   // 8192
#define QKVSTR 3072
#define LNEPS 1e-5f
#define LOG2E_8 0.180336880f   // log2(e)/8

using f32x4 = __attribute__((ext_vector_type(4))) float;
using s16x8 = __attribute__((ext_vector_type(8))) short;
using u16x8 = __attribute__((ext_vector_type(8))) unsigned short;

enum { ACT_NONE = 0, ACT_GELU = 1, ACT_RELU = 2, ACT_SIG = 3 };

__device__ inline float bf2f(unsigned short u) {
    union { unsigned u; float f; } t; t.u = ((unsigned)u) << 16; return t.f;
}
__device__ inline unsigned short f2bf(float f) {
    __hip_bfloat16 h = __float2bfloat16(f);
    return *reinterpret_cast<unsigned short*>(&h);
}
__device__ inline float gelu_f(float t) {
    const float u = t * (0.7978845608f + 0.0356774081f * t * t);
    const float e = __expf(2.f * u);
    const float th = 1.f - 2.f / (e + 1.f);
    return 0.5f * t * (1.f + th);
}

#define GLDS16(g, l) __builtin_amdgcn_global_load_lds( \
    (__attribute__((address_space(1))) void*)(g),      \
    (__attribute__((address_space(3))) void*)(l), 16, 0, 0)
#define MFMA16(a, b, c) __builtin_amdgcn_mfma_f32_16x16x32_bf16(a, b, c, 0, 0, 0)
#define BAR() __builtin_amdgcn_s_barrier()
#define LGKM0() do { asm volatile("s_waitcnt lgkmcnt(0)" ::: "memory"); \
                     __builtin_amdgcn_sched_barrier(0); } while (0)

template<int N> __device__ __forceinline__ void vmwait() {
    asm volatile("s_waitcnt vmcnt(%0)" :: "i"(N) : "memory");
}

// ---------------------------------------------------------------------------
__global__ __launch_bounds__(256)
void cast_bf16_k(const float* __restrict__ in, unsigned short* __restrict__ out, int n4)
{
    for (int i = blockIdx.x * 256 + threadIdx.x; i < n4; i += gridDim.x * 256) {
        float4 v = ((const float4*)in)[i];
        ushort4 o;
        o.x = f2bf(v.x); o.y = f2bf(v.y); o.z = f2bf(v.z); o.w = f2bf(v.w);
        ((ushort4*)out)[i] = o;
    }
}

// ---------------------------------------------------------------------------
__global__ __launch_bounds__(256)
void concat3_k(const float* __restrict__ a, const float* __restrict__ b,
               const float* __restrict__ c, float* __restrict__ o)
{
    int i = blockIdx.x * 256 + threadIdx.x;   // grid 12 -> 3072
    o[i] = i < 1024 ? a[i] : (i < 2048 ? b[i - 1024] : c[i - 2048]);
}

// ---------------------------------------------------------------------------
__global__ __launch_bounds__(256)
void transpose_cast_k(const float* __restrict__ W, unsigned short* __restrict__ Wt,
                      int K, int N)
{
    __shared__ float tile[32][33];
    const int tx = threadIdx.x, ty = threadIdx.y;
    const int k0 = blockIdx.y * 32, n0 = blockIdx.x * 32;
#pragma unroll
    for (int r = 0; r < 32; r += 8)
        tile[ty + r][tx] = W[(size_t)(k0 + ty + r) * N + n0 + tx];
    __syncthreads();
#pragma unroll
    for (int r = 0; r < 32; r += 8)
        Wt[(size_t)(n0 + ty + r) * K + k0 + tx] = f2bf(tile[tx][ty + r]);
}

__global__ __launch_bounds__(256)
void transpose_cast4_k(const float* __restrict__ W0, const float* __restrict__ W1,
                       const float* __restrict__ W2, const float* __restrict__ W3,
                       unsigned short* __restrict__ Wt)
{
    __shared__ float tile[32][33];
    const int z = blockIdx.z;
    const float* W = z == 0 ? W0 : z == 1 ? W1 : z == 2 ? W2 : W3;
    unsigned short* dst = Wt + (size_t)z * HDIM * HDIM;
    const int tx = threadIdx.x, ty = threadIdx.y;
    const int k0 = blockIdx.y * 32, n0 = blockIdx.x * 32;
#pragma unroll
    for (int r = 0; r < 32; r += 8)
        tile[ty + r][tx] = W[(size_t)(k0 + ty + r) * HDIM + n0 + tx];
    __syncthreads();
#pragma unroll
    for (int r = 0; r < 32; r += 8)
        dst[(size_t)(n0 + ty + r) * HDIM + k0 + tx] = f2bf(tile[tx][ty + r]);
}

// ---------------------------------------------------------------------------
__global__ __launch_bounds__(256)
void transpose_v_k(const unsigned short* __restrict__ vb, unsigned short* __restrict__ vtb)
{
    __shared__ unsigned short t[64][72];
    const int tid = threadIdx.x;
    const int b = blockIdx.z, h = blockIdx.y;
    const int s0 = blockIdx.x * 64;
    {
        const int r = tid >> 3, c = (tid & 7) * 8;
        *(u16x8*)&t[r][c] =
            *(const u16x8*)&vb[((size_t)(b * NSEQ + s0 + r)) * QKVSTR + h * DHEAD + c];
        *(u16x8*)&t[r + 32][c] =
            *(const u16x8*)&vb[((size_t)(b * NSEQ + s0 + r + 32)) * QKVSTR + h * DHEAD + c];
    }
    __syncthreads();
    {
        const int d = tid & 63, sc = (tid >> 6) * 16;
        u16x8 o0, o1;
#pragma unroll
        for (int i = 0; i < 8; ++i) o0[i] = t[sc + i][d];
#pragma unroll
        for (int i = 0; i < 8; ++i) o1[i] = t[sc + 8 + i][d];
        unsigned short* dst = &vtb[((size_t)((b * NHEAD + h) * DHEAD + d)) * NSEQ + s0 + sc];
        *(u16x8*)dst = o0;
        *(u16x8*)(dst + 8) = o1;
    }
}

// ---------------------------------------------------------------------------
// High-occupancy GEMM: C[M,N] = act(A[M,K] @ Bt[N,K]^T + bias (+add)).
// BM=128: 128x128 tile, 4 waves 2x2 (64x64 each), 32 KiB LDS.
// BM=64:  64x128 tile, 4 waves 1x4 (64x32 each), 24 KiB LDS (small-N shapes).
// BK=32, 256 threads, static LDS dbuf, granule-XOR swizzle (0 conflicts),
// counted vmcnt. 4 blocks/CU (per-XCD L2 write-set rule from R12).
// ---------------------------------------------------------------------------
template<int BM, int ACT, bool HAS_ADD, bool OUT_BF>
__global__ __launch_bounds__(256, 4)
void gemm_hi_k(const unsigned short* __restrict__ A, const unsigned short* __restrict__ Bt,
               const float* __restrict__ bias, const float* __restrict__ add,
               void* __restrict__ Cv, int M, int N, int K, int nbx)
{
    constexpr int NREP = (BM == 128) ? 4 : 2;
    constexpr int AR = BM / 64;        // A stage loads
    constexpr int VM = AR + 2;         // loads per stage (A + 2 B)
    __shared__ alignas(16) unsigned short As[2][BM * 32];
    __shared__ alignas(16) unsigned short Bs[2][128 * 32];

    const int tid = threadIdx.x;
    const int lane = tid & 63;
    const int w = tid >> 6;
    const int wr = (BM == 128) ? (w >> 1) : 0;
    const int wcb = (BM == 128) ? ((w & 1) * 64) : (w * 32);   // wave col base
    const int chunk = gridDim.x >> 3;
    const int wg = (blockIdx.x & 7) * chunk + (blockIdx.x >> 3);
    const int m0 = (wg / nbx) * BM;
    const int n0 = (wg % nbx) * 128;

    const int fr = lane & 15;
    const int fo = lane >> 4;
    const int fo_swz8 = (fo ^ ((fr >> 1) & 3)) * 8;

    const int srow = tid >> 2;                      // 0..63
    const int sg8 = ((tid & 3) ^ ((tid >> 3) & 3)) * 8;

    f32x4 acc[4][NREP] = {};

    auto stage = [&](int t) {
        const int buf = t & 1;
        const unsigned short* as_ = A + (size_t)(m0 + srow) * K + t * 32 + sg8;
        const unsigned short* bs_ = Bt + (size_t)(n0 + srow) * K + t * 32 + sg8;
        GLDS16(as_, &As[buf][(w * 16) * 32]);
        if constexpr (BM == 128)
            GLDS16(as_ + (size_t)64 * K, &As[buf][(64 + w * 16) * 32]);
        GLDS16(bs_, &Bs[buf][(w * 16) * 32]);
        GLDS16(bs_ + (size_t)64 * K, &Bs[buf][(64 + w * 16) * 32]);
    };

    const int NT = K / 32;
    stage(0);

    for (int t = 0; t < NT; ++t) {
        if (t + 1 < NT) { stage(t + 1); vmwait<VM>(); }
        else            { vmwait<0>(); }
        BAR();

        const int buf = t & 1;
        s16x8 af[4], bf[NREP];
#pragma unroll
        for (int i = 0; i < 4; ++i)
            af[i] = *(const s16x8*)(&As[buf][(wr * 64 + i * 16 + fr) * 32 + fo_swz8]);
#pragma unroll
        for (int j = 0; j < NREP; ++j)
            bf[j] = *(const s16x8*)(&Bs[buf][(wcb + j * 16 + fr) * 32 + fo_swz8]);

        __builtin_amdgcn_s_setprio(1);
#pragma unroll
        for (int i = 0; i < 4; ++i)
#pragma unroll
            for (int j = 0; j < NREP; ++j)
                acc[i][j] = MFMA16(af[i], bf[j], acc[i][j]);
        __builtin_amdgcn_s_setprio(0);

        LGKM0();
        BAR();
    }

    float bv[NREP];
#pragma unroll
    for (int j = 0; j < NREP; ++j)
        bv[j] = bias[n0 + wcb + j * 16 + fr];
#pragma unroll
    for (int i = 0; i < 4; ++i) {
#pragma unroll
        for (int j = 0; j < NREP; ++j) {
            const int gn = n0 + wcb + j * 16 + fr;
#pragma unroll
            for (int r = 0; r < 4; ++r) {
                const int gm = m0 + wr * 64 + i * 16 + fo * 4 + r;
                float t = acc[i][j][r] + bv[j];
                if (HAS_ADD) t += add[(size_t)gm * N + gn];
                if (ACT == ACT_GELU)      t = gelu_f(t);
                else if (ACT == ACT_RELU) t = fmaxf(t, 0.f);
                else if (ACT == ACT_SIG)  t = 1.f / (1.f + __expf(-t));
                if (OUT_BF) ((unsigned short*)Cv)[(size_t)gm * N + gn] = f2bf(t);
                else        ((float*)Cv)[(size_t)gm * N + gn] = t;
            }
        }
    }
}

// ---------------------------------------------------------------------------
// MFMA flash attention v3 (round-8, unchanged).
// ---------------------------------------------------------------------------
__global__ __launch_bounds__(512, 6)
void attn_k(const unsigned short* __restrict__ QKVb, const unsigned short* __restrict__ Vtb,
            unsigned short* __restrict__ Cb)
{
    __shared__ alignas(16) unsigned short Ks[2][64 * 64];
    __shared__ alignas(16) unsigned short Vs[2][64 * 64];
    __shared__ alignas(16) unsigned short Ps[8][16 * 72];

    const int tid = threadIdx.x;
    const int lane = tid & 63;
    const int wid = tid >> 6;
    const int L = blockIdx.x;
    const int xcd = L & 7, s = L >> 3;
    const int bh = xcd + ((s >> 3) << 3);
    const int qt = s & 7;
    const int b = bh >> 4, h = bh & 15;
    const int q0 = qt * 128 + wid * 16;

    const int kcol = lane & 15;
    const int kofs = (lane >> 4) * 8;
    const size_t qoff = ((size_t)(b * NSEQ + q0 + kcol)) * QKVSTR + h * DHEAD + kofs;
    const s16x8 qf0 = *(const s16x8*)(QKVb + qoff);
    const s16x8 qf1 = *(const s16x8*)(QKVb + qoff + 32);

    f32x4 accO[4] = {};
    float mrow[4] = {-1e30f, -1e30f, -1e30f, -1e30f};
    float lsum[4] = {0.f, 0.f, 0.f, 0.f};

    const int lr = lane >> 3;
    const int swz8 = (((lane & 7) ^ lr)) * 8;
    const size_t kbase  = ((size_t)(b * NSEQ)) * QKVSTR + HDIM + h * DHEAD;
    const size_t vtbase = ((size_t)(bh * DHEAD)) * NSEQ;

    unsigned short* const pw = &Ps[wid][0];
    const int prow = (lane >> 4) * 4;

    auto stage = [&](int kt, int buf) {
        const int rowb = wid * 8;
        GLDS16(QKVb + kbase + (size_t)(kt * 64 + rowb + lr) * QKVSTR + swz8,
               Ks[buf] + rowb * 64);
        GLDS16(Vtb + vtbase + (size_t)(rowb + lr) * NSEQ + kt * 64 + swz8,
               Vs[buf] + rowb * 64);
    };

    stage(0, 0);
    asm volatile("s_waitcnt vmcnt(0)" ::: "memory");
    __syncthreads();

    for (int kt = 0; kt < NSEQ / 64; ++kt) {
        const int cur = kt & 1;
        if (kt + 1 < NSEQ / 64) stage(kt + 1, cur ^ 1);

        f32x4 sa[4];
#pragma unroll
        for (int jt = 0; jt < 4; ++jt) {
            const int kr = jt * 16 + kcol;
            const unsigned swz = ((unsigned)(kr & 7)) << 4;
            const s16x8 kf0 = *(const s16x8*)((const char*)Ks[cur] + kr * 128 + ((kofs * 2) ^ swz));
            const s16x8 kf1 = *(const s16x8*)((const char*)Ks[cur] + kr * 128 + ((64 + kofs * 2) ^ swz));
            f32x4 t = {};
            t = MFMA16(qf0, kf0, t);
            t = MFMA16(qf1, kf1, t);
            sa[jt] = t * LOG2E_8;
        }

        float lmax[4];
#pragma unroll
        for (int r = 0; r < 4; ++r)
            lmax[r] = fmaxf(fmaxf(sa[0][r], sa[1][r]), fmaxf(sa[2][r], sa[3][r]));
        const float guard = fmaxf(fmaxf(lmax[0] - mrow[0], lmax[1] - mrow[1]),
                                  fmaxf(lmax[2] - mrow[2], lmax[3] - mrow[3]));
        if (!__all(guard <= 8.f)) {
#pragma unroll
            for (int r = 0; r < 4; ++r) {
                float m = lmax[r];
                m = fmaxf(m, __shfl_xor(m, 1));
                m = fmaxf(m, __shfl_xor(m, 2));
                m = fmaxf(m, __shfl_xor(m, 4));
                m = fmaxf(m, __shfl_xor(m, 8));
                const float mn = fmaxf(mrow[r], m);
                const float corr = exp2f(mrow[r] - mn);
                mrow[r] = mn;
                lsum[r] *= corr;
#pragma unroll
                for (int dt = 0; dt < 4; ++dt) accO[dt][r] *= corr;
            }
        }
#pragma unroll
        for (int r = 0; r < 4; ++r) {
#pragma unroll
            for (int jt = 0; jt < 4; ++jt) {
                const float p = exp2f(sa[jt][r] - mrow[r]);
                pw[(prow + r) * 72 + jt * 16 + kcol] = f2bf(p);
                lsum[r] += p;
            }
        }

#pragma unroll
        for (int kc = 0; kc < 2; ++kc) {
            const s16x8 pa = *(const s16x8*)(pw + kcol * 72 + kc * 32 + kofs);
#pragma unroll
            for (int dt = 0; dt < 4; ++dt) {
                const int dr = dt * 16 + kcol;
                const unsigned swz = ((unsigned)(dr & 7)) << 4;
                const s16x8 vf = *(const s16x8*)((const char*)Vs[cur] + dr * 128 +
                                                 ((kc * 64 + kofs * 2) ^ swz));
                accO[dt] = MFMA16(pa, vf, accO[dt]);
            }
        }

        if (kt + 1 < NSEQ / 64) asm volatile("s_waitcnt vmcnt(0)" ::: "memory");
        __builtin_amdgcn_s_barrier();
    }

#pragma unroll
    for (int r = 0; r < 4; ++r) {
        lsum[r] += __shfl_xor(lsum[r], 1);
        lsum[r] += __shfl_xor(lsum[r], 2);
        lsum[r] += __shfl_xor(lsum[r], 4);
        lsum[r] += __shfl_xor(lsum[r], 8);
    }

    const size_t obase = ((size_t)(b * NSEQ + q0 + prow)) * HDIM + h * DHEAD;
#pragma unroll
    for (int r = 0; r < 4; ++r) {
        const float rl = 1.f / lsum[r];
#pragma unroll
        for (int dt = 0; dt < 4; ++dt)
            Cb[obase + (size_t)r * HDIM + dt * 16 + kcol] = f2bf(accO[dt][r] * rl);
    }
}

// ---------------------------------------------------------------------------
// ada-LayerNorm. MODE 0: y = a (fp32), writes bf16 copy.
// MODE 1: y = a*(2-g) + fo*g with fo,g read as bf16.
// ---------------------------------------------------------------------------
template<int MODE, bool WRITE_BF>
__global__ __launch_bounds__(256)
void adaln_k(const float* __restrict__ a,
             const unsigned short* __restrict__ fo_bf,
             const unsigned short* __restrict__ g_bf,
             const float* __restrict__ vol,
             const float* __restrict__ lw, const float* __restrict__ lb,
             const float* __restrict__ gm, const float* __restrict__ bt,
             const float* __restrict__ vsw, const float* __restrict__ vsb,
             float* __restrict__ out, unsigned short* __restrict__ out_bf)
{
    const int tok = blockIdx.x;
    const int tid = threadIdx.x;
    const size_t base = (size_t)tok * HDIM + tid * 4;
    float v[4];
    {
        float4 va = *(const float4*)&a[base];
        if (MODE == 1) {
            ushort4 uf = *(const ushort4*)&fo_bf[base];
            ushort4 ug = *(const ushort4*)&g_bf[base];
            float f0 = bf2f(uf.x), f1 = bf2f(uf.y), f2 = bf2f(uf.z), f3 = bf2f(uf.w);
            float g0 = bf2f(ug.x), g1 = bf2f(ug.y), g2 = bf2f(ug.z), g3 = bf2f(ug.w);
            v[0] = va.x * (2.f - g0) + f0 * g0;
            v[1] = va.y * (2.f - g1) + f1 * g1;
            v[2] = va.z * (2.f - g2) + f2 * g2;
            v[3] = va.w * (2.f - g3) + f3 * g3;
        } else {
            v[0] = va.x; v[1] = va.y; v[2] = va.z; v[3] = va.w;
        }
    }
    float sum = v[0] + v[1] + v[2] + v[3];
    float sq  = v[0]*v[0] + v[1]*v[1] + v[2]*v[2] + v[3]*v[3];
#pragma unroll
    for (int off = 32; off > 0; off >>= 1) {
        sum += __shfl_down(sum, off);
        sq  += __shfl_down(sq, off);
    }
    __shared__ float ssum[4], ssq[4];
    const int wid = tid >> 6, lane = tid & 63;
    if (lane == 0) { ssum[wid] = sum; ssq[wid] = sq; }
    __syncthreads();
    const float tsum = ssum[0] + ssum[1] + ssum[2] + ssum[3];
    const float tsq  = ssq[0]  + ssq[1]  + ssq[2]  + ssq[3];
    const float mu   = tsum * (1.f / 1024.f);
    const float var  = tsq * (1.f / 1024.f) - mu * mu;
    const float rstd = rsqrtf(var + LNEPS);
    const float vsv  = 1.f / (1.f + __expf(-(vol[tok] * vsw[0] + vsb[0])));
    const float sca  = (1.f + vsv) * gm[0];
    const float off2 = bt[0];
    const float4 lwv = *(const float4*)&lw[tid * 4];
    const float4 lbv = *(const float4*)&lb[tid * 4];
    float r0 = ((v[0] - mu) * rstd * lwv.x + lbv.x) * sca + off2;
    float r1 = ((v[1] - mu) * rstd * lwv.y + lbv.y) * sca + off2;
    float r2 = ((v[2] - mu) * rstd * lwv.z + lbv.z) * sca + off2;
    float r3 = ((v[3] - mu) * rstd * lwv.w + lbv.w) * sca + off2;
    *(float4*)&out[base] = make_float4(r0, r1, r2, r3);
    if (WRITE_BF) {
        ushort4 ob;
        ob.x = f2bf(r0); ob.y = f2bf(r1); ob.z = f2bf(r2); ob.w = f2bf(r3);
        *(ushort4*)&out_bf[base] = ob;
    }
}

// ---------------------------------------------------------------------------
extern "C" void kernel_launch(void* const* d_in, const int* in_sizes, int n_in,
                              void* d_out, int out_size, void* d_ws, size_t ws_size,
                              hipStream_t stream)
{
    (void)in_sizes; (void)n_in; (void)out_size; (void)ws_size;
    const float* x    = (const float*)d_in[0];
    const float* vol  = (const float*)d_in[1];
    const float* Wq   = (const float*)d_in[2];  const float* bq  = (const float*)d_in[3];
    const float* Wk   = (const float*)d_in[4];  const float* bk  = (const float*)d_in[5];
    const float* Wv   = (const float*)d_in[6];  const float* bv  = (const float*)d_in[7];
    const float* Wo   = (const float*)d_in[8];  const float* bo  = (const float*)d_in[9];
    const float* ln1w = (const float*)d_in[10]; const float* ln1b = (const float*)d_in[11];
    const float* gm1  = (const float*)d_in[12]; const float* be1 = (const float*)d_in[13];
    const float* vs1w = (const float*)d_in[14]; const float* vs1b = (const float*)d_in[15];
    const float* fw1  = (const float*)d_in[16]; const float* fb1 = (const float*)d_in[17];
    const float* fw2  = (const float*)d_in[18]; const float* fb2 = (const float*)d_in[19];
    const float* gw1  = (const float*)d_in[20]; const float* gb1 = (const float*)d_in[21];
    const float* gw2  = (const float*)d_in[22]; const float* gb2 = (const float*)d_in[23];
    const float* ln2w = (const float*)d_in[24]; const float* ln2b = (const float*)d_in[25];
    const float* gm2  = (const float*)d_in[26]; const float* be2 = (const float*)d_in[27];
    const float* vs2w = (const float*)d_in[28]; const float* vs2b = (const float*)d_in[29];

    char* w = (char*)d_ws;
    auto MB = [](size_t v) { return v << 20; };
    unsigned short* wtqkv = (unsigned short*)(w + MB(0));   // 0-6
    unsigned short* wto   = (unsigned short*)(w + MB(6));   // 6-8
    unsigned short* wtf1  = (unsigned short*)(w + MB(8));   // 8-16
    unsigned short* wtf2  = (unsigned short*)(w + MB(16));  // 16-24
    unsigned short* wtg1  = (unsigned short*)(w + MB(24));  // 24-25
    unsigned short* wtg2  = (unsigned short*)(w + MB(25));  // 25-26
    unsigned short* xb   = (unsigned short*)(w + MB(26));   // 26-42
    unsigned short* qkvb = (unsigned short*)(w + MB(42));   // 42-90
    unsigned short* vtb  = (unsigned short*)(w + MB(90));   // 90-106
    unsigned short* cxb  = (unsigned short*)(w + MB(106));  // 106-122
    float*          ao   = (float*)(w + MB(122));           // 122-154
    float*          x1   = (float*)(w + MB(42));            // 42-74 (qkvb dead)
    unsigned short* x1b  = (unsigned short*)(w + MB(74));   // 74-90
    unsigned short* hb   = (unsigned short*)(w + MB(90));   // 90-154 (vtb/cxb/ao dead)
    unsigned short* ffnb = (unsigned short*)(w + MB(154));  // 154-170
    unsigned short* ghb  = (unsigned short*)(w + MB(170));  // 170-178
    unsigned short* ggb  = (unsigned short*)(w + MB(26));   // 26-42 (xb dead)
    float*          bqkv = (float*)(w + MB(184));

    dim3 blk(256);
    dim3 tb(32, 8);
    transpose_cast4_k<<<dim3(32, 32, 4), tb, 0, stream>>>(Wq, Wk, Wv, Wo, wtqkv);
    transpose_cast_k<<<dim3(4096/32, 1024/32), tb, 0, stream>>>(fw1, wtf1, 1024, 4096);
    transpose_cast_k<<<dim3(1024/32, 4096/32), tb, 0, stream>>>(fw2, wtf2, 4096, 1024);
    transpose_cast_k<<<dim3(512/32, 1024/32),  tb, 0, stream>>>(gw1, wtg1, 1024, 512);
    transpose_cast_k<<<dim3(1024/32, 512/32),  tb, 0, stream>>>(gw2, wtg2, 512, 1024);
    cast_bf16_k<<<2048, blk, 0, stream>>>(x, xb, NTOK * HDIM / 4);
    concat3_k<<<12, blk, 0, stream>>>(bq, bk, bv, bqkv);

    // QKV: BM=128, grid 24*64 = 1536
    gemm_hi_k<128, ACT_NONE, false, true><<<dim3(24 * 64), blk, 0, stream>>>(
        xb, wtqkv, bqkv, nullptr, qkvb, NTOK, QKVSTR, HDIM, 24);
    transpose_v_k<<<dim3(NSEQ / 64, NHEAD, NBATCH), blk, 0, stream>>>(qkvb + 2048, vtb);
    attn_k<<<dim3(1024), 512, 0, stream>>>(qkvb, vtb, cxb);
    // Wo (+residual): BM=64, grid 128*8 = 1024 (full fill)
    gemm_hi_k<64, ACT_NONE, true, false><<<dim3(128 * 8), blk, 0, stream>>>(
        cxb, wto, bo, x, ao, NTOK, HDIM, HDIM, 8);
    adaln_k<0, true><<<dim3(NTOK), blk, 0, stream>>>(
        ao, nullptr, nullptr, vol, ln1w, ln1b, gm1, be1, vs1w, vs1b, x1, x1b);
    // FFN1: BM=128, grid 32*64 = 2048
    gemm_hi_k<128, ACT_GELU, false, true><<<dim3(32 * 64), blk, 0, stream>>>(
        x1b, wtf1, fb1, nullptr, hb, NTOK, 4096, HDIM, 32);
    // FFN2: BM=64, grid 1024, bf16 out
    gemm_hi_k<64, ACT_NONE, false, true><<<dim3(128 * 8), blk, 0, stream>>>(
        hb, wtf2, fb2, nullptr, ffnb, NTOK, HDIM, 4096, 8);
    // gate1: BM=64, grid 128*4 = 512
    gemm_hi_k<64, ACT_RELU, false, true><<<dim3(128 * 4), blk, 0, stream>>>(
        x1b, wtg1, gb1, nullptr, ghb, NTOK, 512, HDIM, 4);
    // gate2: BM=64, grid 1024, bf16 out
    gemm_hi_k<64, ACT_SIG, false, true><<<dim3(128 * 8), blk, 0, stream>>>(
        ghb, wtg2, gb2, nullptr, ggb, NTOK, HDIM, 512, 8);
    adaln_k<1, false><<<dim3(NTOK), blk, 0, stream>>>(
        x1, ffnb, ggb, vol, ln2w, ln2b, gm2, be2, vs2w, vs2b, (float*)d_out, nullptr);
}